// Round 15
// baseline (107.297 us; speedup 1.0000x reference)
//
#include <hip/hip_runtime.h>

// CPAMDec — R15: producer/consumer wave specialization. 512-thread blocks:
// waves 4-7 stage x tiles (issue-early/write-late, double-buffered LDS);
// waves 0-3 compute energy MFMA -> softmax -> PV MFMA -> store, one 16-px
// tile per iteration (4 tiles/block). Breaks the chip-wide phase lockstep so
// HBM-read, LDS/MFMA, VALU, HBM-write run concurrently.
// Frag layouts (mfma_f32_16x16x32_bf16), HW-verified R5/R6:
//   A[m][k]: lane l -> m=l&15, k=8*(l>>4)+j ; B[k][n]: lane l -> n=l&15, k=8*(l>>4)+j
//   D[m][n]: lane l -> n=l&15, m=4*(l>>4)+r
// xl 16-px padded subtile: f(c,px) = (c>>5)*576 + ((c>>3)&3)*144 + ((c>>2)&1)*64
//                                  + (c&3)*16 + px      (per-buffer 9216 elems)
// ws: wqkf bf16[N][32*512] @0 (256K) | vtf bf16[N][32*512] @256K | bqk f32[256] @512K

#define N_  8
#define C_  512
#define HW_ 4096
#define K_  32

typedef __attribute__((ext_vector_type(8))) short bf16x8;
typedef __attribute__((ext_vector_type(4))) float f32x4;
typedef __attribute__((ext_vector_type(2))) int i32x2;
typedef __attribute__((ext_vector_type(4))) int i32x4;

__device__ __forceinline__ unsigned short f2b(float f) {
    union { float f; unsigned u; } v; v.f = f;
    unsigned r = v.u + 0x7FFFu + ((v.u >> 16) & 1u);   // RNE
    return (unsigned short)(r >> 16);
}
__device__ __forceinline__ float b2f(unsigned short h) {
    union { unsigned u; float f; } v; v.u = ((unsigned)h) << 16; return v.f;
}

// wqk frag slot: wqk[kk][c] -> elem ((cs*2+kt)*64 + g*16 + (kk&15))*8 + j
__device__ __forceinline__ int wqk_idx(int kk, int c) {
    return ((((c >> 5) * 2 + (kk >> 4)) * 64 + ((c >> 3) & 3) * 16 + (kk & 15)) << 3) + (c & 7);
}

__global__ __launch_bounds__(256) void prep_kernel(
    const float* __restrict__ y, const float* __restrict__ wq, const float* __restrict__ bq,
    const float* __restrict__ wk, const float* __restrict__ bk,
    const float* __restrict__ wv, const float* __restrict__ bv,
    unsigned short* __restrict__ wqkf, float* __restrict__ bqk, unsigned short* __restrict__ vtf)
{
    const int bid = blockIdx.x;
    const int t = threadIdx.x;

    if (bid < 256) {
        // role A: v rows -> vtf frags. block = (n, ct of 16 c).
        __shared__ float vred[3][4][16][8];              // 6 KB
        const int n   = bid >> 5;
        const int ct  = bid & 31;
        const int cl  = t & 15;
        const int kko = (t >> 4) & 3;
        const int jq4 = t >> 6;
        const int c   = ct * 16 + cl;

        const float* yb  = y  + ((size_t)n * K_ + kko * 8) * C_ + jq4 * 128;
        const float* wvb = wv + (size_t)c * C_ + jq4 * 128;
        float acc[8] = {0,0,0,0,0,0,0,0};
        #pragma unroll 4
        for (int jj = 0; jj < 32; ++jj) {
            float4 w4 = *(const float4*)(wvb + jj * 4);
            #pragma unroll
            for (int u = 0; u < 8; ++u) {
                float4 y4 = *(const float4*)(yb + (size_t)u * C_ + jj * 4);
                acc[u] += y4.x * w4.x + y4.y * w4.y + y4.z * w4.z + y4.w * w4.w;
            }
        }
        if (jq4 > 0) {
            #pragma unroll
            for (int u = 0; u < 8; ++u) vred[jq4 - 1][kko][cl][u] = acc[u];
        }
        __syncthreads();
        if (jq4 == 0) {
            const float bvc = bv[c];
            unsigned short o[8];
            #pragma unroll
            for (int u = 0; u < 8; ++u) {
                float s = acc[u] + vred[0][kko][cl][u] + vred[1][kko][cl][u]
                        + vred[2][kko][cl][u] + bvc;
                o[u] = f2b(s);
            }
            i32x4 pk = { (int)(o[0] | ((unsigned)o[1] << 16)), (int)(o[2] | ((unsigned)o[3] << 16)),
                         (int)(o[4] | ((unsigned)o[5] << 16)), (int)(o[6] | ((unsigned)o[7] << 16)) };
            *(i32x4*)(vtf + (size_t)n * (K_ * C_) + (size_t)((ct * 64 + kko * 16 + cl) * 8)) = pk;
        }
    } else {
        // role B: krow -> bqk, wqk frags. block = (n, kk)
        __shared__ __align__(16) float kp[2][128];
        __shared__ __align__(16) float kr[128];
        const int b = bid - 256;
        const int n = b >> 5, kk = b & 31;
        const int o = t & 127, half = t >> 7;

        const float* yb  = y  + ((size_t)n * K_ + kk) * C_ + half * 256;
        const float* wkb = wk + (size_t)o * C_ + half * 256;
        float a = 0.f;
        #pragma unroll 4
        for (int jq = 0; jq < 64; ++jq) {
            float4 w4 = *(const float4*)(wkb + jq * 4);
            float4 y4 = *(const float4*)(yb + jq * 4);
            a += y4.x * w4.x + y4.y * w4.y + y4.z * w4.z + y4.w * w4.w;
        }
        kp[half][o] = a;
        __syncthreads();
        if (t < 128) kr[t] = kp[0][t] + kp[1][t] + bk[t];
        __syncthreads();
        if (t < 64) {
            float s = kr[t] * bq[t] + kr[t + 64] * bq[t + 64];
            #pragma unroll
            for (int d = 32; d > 0; d >>= 1) s += __shfl_down(s, d);
            if (t == 0) bqk[n * K_ + kk] = s;
        }
        const int c1 = t, c2 = t + 256;
        float s1 = 0.f, s2 = 0.f;
        for (int oq = 0; oq < 32; ++oq) {
            float4 k4 = *(const float4*)(&kr[oq * 4]);
            const float* wq0 = wq + (size_t)(oq * 4) * C_;
            s1 += k4.x * wq0[c1] + k4.y * wq0[C_ + c1] + k4.z * wq0[2*C_ + c1] + k4.w * wq0[3*C_ + c1];
            s2 += k4.x * wq0[c2] + k4.y * wq0[C_ + c2] + k4.z * wq0[2*C_ + c2] + k4.w * wq0[3*C_ + c2];
        }
        unsigned short* wqf_n = wqkf + (size_t)n * (K_ * C_);
        wqf_n[wqk_idx(kk, c1)] = f2b(s1);
        wqf_n[wqk_idx(kk, c2)] = f2b(s2);
    }
}

__global__ __launch_bounds__(512, 4) void main_kernel(
    const float* __restrict__ x, const unsigned short* __restrict__ wqkf,
    const unsigned short* __restrict__ vtf, const float* __restrict__ bqk,
    const float* __restrict__ scale, float* __restrict__ out)
{
    __shared__ __align__(16) unsigned short xl[2][9216];  // 36 KB dbuf 16-px tiles
    __shared__ float e_lds[16][33];                        // 2.1 KB

    // XCD swizzle: 64 consecutive blocks (= one image n) per XCD
    const int swz = (blockIdx.x & 7) * 64 + (blockIdx.x >> 3);
    const int n   = swz >> 6;
    const int py0 = (swz & 63) * 64;          // block covers 64 px = 4 tiles of 16
    const int t  = threadIdx.x;
    const int w  = t >> 6, l = t & 63;
    const int l15 = l & 15, lg = l >> 4;
    const float* xg = x + (size_t)n * C_ * HW_;
    float* og = out + (size_t)n * C_ * HW_;
    const unsigned short* wqf  = wqkf + (size_t)n * (K_ * C_);
    const unsigned short* vtfn = vtf  + (size_t)n * (K_ * C_);
    const bool producer = (w >= 4);

    // producer mapping: tp in 0..255 -> px4 = (tp&3)*4, c = (tp>>2) + 64*u
    const int tp = t & 255;
    const int px4 = (tp & 3) * 4;
    const int crow = tp >> 2;

    const float fs = scale[0];
    const float bq_ = bqk[n * K_ + (w & 1) * 16 + l15];

    // consumers: hoist vtf A-frags for this wave's c-quarter (reused all tiles)
    bf16x8 vf[8];
    if (!producer) {
        #pragma unroll
        for (int mi = 0; mi < 8; ++mi)
            vf[mi] = *(const bf16x8*)(vtfn + ((size_t)(w * 8 + mi) * 64 + l) * 8);
    }

    // ---- prologue: producers stage tile 0 into xl[0] ----
    if (producer) {
        const float* xs = xg + py0 + px4;
        float4 r[8];
        #pragma unroll
        for (int u = 0; u < 8; ++u)
            r[u] = *(const float4*)(xs + (size_t)(crow + 64 * u) * HW_);
        #pragma unroll
        for (int u = 0; u < 8; ++u) {
            const int c = crow + 64 * u;
            const int off = (c >> 5) * 576 + ((c >> 3) & 3) * 144 + ((c >> 2) & 1) * 64
                          + (c & 3) * 16 + px4;
            i32x2 pk = { (int)(f2b(r[u].x) | ((unsigned)f2b(r[u].y) << 16)),
                         (int)(f2b(r[u].z) | ((unsigned)f2b(r[u].w) << 16)) };
            *(i32x2*)(&xl[0][off]) = pk;
        }
    }
    __syncthreads();

    float4 pr[8];                                  // producer in-flight regs
    for (int i = 0; i < 4; ++i) {
        const unsigned short* xb = xl[i & 1];

        if (producer) {
            if (i < 3) {                           // issue loads for tile i+1 (write later)
                const float* xs = xg + py0 + (i + 1) * 16 + px4;
                #pragma unroll
                for (int u = 0; u < 8; ++u)
                    pr[u] = *(const float4*)(xs + (size_t)(crow + 64 * u) * HW_);
            }
        } else if (w < 2) {
            // ---- energy MFMA: kt = w, full K=512, B-frag depth-2 prefetch ----
            const int kt = w;
            bf16x8 b0 = *(const bf16x8*)(wqf + ((size_t)(0 * 2 + kt) * 64 + l) * 8);
            bf16x8 b1 = *(const bf16x8*)(wqf + ((size_t)(1 * 2 + kt) * 64 + l) * 8);
            f32x4 acc = {0.f, 0.f, 0.f, 0.f};
            for (int cs = 0; cs < 16; ++cs) {
                bf16x8 b2;
                if (cs < 14) b2 = *(const bf16x8*)(wqf + ((size_t)((cs + 2) * 2 + kt) * 64 + l) * 8);
                const unsigned short* xp = xb + cs * 576 + lg * 144 + l15;
                const unsigned e0 = xp[0],  e1 = xp[16], e2 = xp[32],  e3 = xp[48];
                const unsigned e4 = xp[64], e5 = xp[80], e6 = xp[96],  e7 = xp[112];
                union { unsigned u[4]; bf16x8 v; } af;
                af.u[0] = e0 | (e1 << 16);  af.u[1] = e2 | (e3 << 16);
                af.u[2] = e4 | (e5 << 16);  af.u[3] = e6 | (e7 << 16);
                acc = __builtin_amdgcn_mfma_f32_16x16x32_bf16(af.v, b0, acc, 0, 0, 0);
                b0 = b1; b1 = b2;
            }
            #pragma unroll
            for (int r = 0; r < 4; ++r)
                e_lds[lg * 4 + r][kt * 16 + l15] = acc[r] + bq_;
        }
        __syncthreads();

        if (producer) {
            if (i < 3) {                           // write tile i+1 into other buffer
                unsigned short* xw = xl[(i + 1) & 1];
                #pragma unroll
                for (int u = 0; u < 8; ++u) {
                    const int c = crow + 64 * u;
                    const int off = (c >> 5) * 576 + ((c >> 3) & 3) * 144 + ((c >> 2) & 1) * 64
                                  + (c & 3) * 16 + px4;
                    i32x2 pk = { (int)(f2b(pr[u].x) | ((unsigned)f2b(pr[u].y) << 16)),
                                 (int)(f2b(pr[u].z) | ((unsigned)f2b(pr[u].w) << 16)) };
                    *(i32x2*)(&xw[off]) = pk;
                }
            }
        } else {
            // ---- softmax (per-lane, row l15) + PV + store ----
            bf16x8 paf;
            {
                float e[32];
                #pragma unroll
                for (int k = 0; k < 32; ++k) e[k] = e_lds[l15][k];
                float mx = e[0];
                #pragma unroll
                for (int k = 1; k < 32; ++k) mx = fmaxf(mx, e[k]);
                float s = 0.f;
                #pragma unroll
                for (int k = 0; k < 32; ++k) { e[k] = __expf(e[k] - mx); s += e[k]; }
                const float inv = 1.f / s;
                #pragma unroll
                for (int j = 0; j < 8; ++j) paf[j] = (short)f2b(e[8 * lg + j] * inv);
            }
            const int p0i = py0 + i * 16;
            #pragma unroll
            for (int mi = 0; mi < 8; ++mi) {
                const int mt = w * 8 + mi;
                f32x4 d = __builtin_amdgcn_mfma_f32_16x16x32_bf16(vf[mi], paf, (f32x4){0.f,0.f,0.f,0.f}, 0, 0, 0);
                const int base = (mt >> 1) * 576 + ((2 * mt + (lg >> 1)) & 3) * 144
                               + (lg & 1) * 64 + l15;
                const int cc = mt * 16 + lg * 4;
                #pragma unroll
                for (int r = 0; r < 4; ++r) {
                    const float xr = b2f(xb[base + r * 16]);
                    og[(size_t)(cc + r) * HW_ + p0i + l15] = fs * d[r] + xr;
                }
            }
        }
        __syncthreads();
    }
}

extern "C" void kernel_launch(void* const* d_in, const int* in_sizes, int n_in,
                              void* d_out, int out_size, void* d_ws, size_t ws_size,
                              hipStream_t stream) {
    const float* x     = (const float*)d_in[0];
    const float* y     = (const float*)d_in[1];
    const float* wq    = (const float*)d_in[2];
    const float* bq    = (const float*)d_in[3];
    const float* wk    = (const float*)d_in[4];
    const float* bk    = (const float*)d_in[5];
    const float* wv    = (const float*)d_in[6];
    const float* bv    = (const float*)d_in[7];
    const float* scale = (const float*)d_in[8];

    unsigned short* wqkf = (unsigned short*)d_ws;                       // 256 KB
    unsigned short* vtf  = wqkf + (size_t)N_ * K_ * C_;                 // 256 KB
    float* bqk = (float*)((char*)d_ws + 524288);                        // 1 KB

    prep_kernel<<<512, 256, 0, stream>>>(y, wq, bq, wk, bk, wv, bv, wqkf, bqk, vtf);
    main_kernel<<<512, 512, 0, stream>>>(x, wqkf, vtf, bqk, scale, (float*)d_out);
}

// Round 16
// 74.163 us; speedup vs baseline: 1.4468x; 1.4468x over previous
//
#include <hip/hip_runtime.h>

// CPAMDec — R16: phase-decoupled pipeline. prep -> energy_kernel (R14 phases
// 0-2 + attf store) -> pv_kernel (R13 phase 3, barrier-free, LDS-free).
// Breaks the intra-block barrier lockstep that pinned fused mains at ~44-48us.
// Frag layouts (mfma_f32_16x16x32_bf16), HW-verified R5/R6:
//   A[m][k]: lane l -> m=l&15, k=8*(l>>4)+j ; B[k][n]: lane l -> n=l&15, k=8*(l>>4)+j
//   D[m][n]: lane l -> n=l&15, m=4*(l>>4)+r
// xl padded subtile: elem(c,px) = (c>>5)*1088 + ((c>>3)&3)*272 + ((c>>2)&1)*128
//                              + (c&3)*16 + ((px>>4)&1)*64 + (px&15)
// attf B-frag: attf[n][(ptile*64 + l)*8 + j] = attn[kk=8*(l>>4)+j][px=ptile*16+(l&15)]
// ws: wqkf bf16[N][32*512] @0 | vtf bf16[N][32*512] @256K | bqk f32[256] @512K
//     attf bf16[N][256*64*8] @525312 (2 MB)

#define N_  8
#define C_  512
#define HW_ 4096
#define K_  32

typedef __attribute__((ext_vector_type(8))) short bf16x8;
typedef __attribute__((ext_vector_type(4))) float f32x4;
typedef __attribute__((ext_vector_type(2))) int i32x2;
typedef __attribute__((ext_vector_type(4))) int i32x4;

__device__ __forceinline__ unsigned short f2b(float f) {
    union { float f; unsigned u; } v; v.f = f;
    unsigned r = v.u + 0x7FFFu + ((v.u >> 16) & 1u);   // RNE
    return (unsigned short)(r >> 16);
}

// wqk frag slot: wqk[kk][c] -> elem ((cs*2+kt)*64 + g*16 + (kk&15))*8 + j
__device__ __forceinline__ int wqk_idx(int kk, int c) {
    return ((((c >> 5) * 2 + (kk >> 4)) * 64 + ((c >> 3) & 3) * 16 + (kk & 15)) << 3) + (c & 7);
}

__global__ __launch_bounds__(256) void prep_kernel(
    const float* __restrict__ y, const float* __restrict__ wq, const float* __restrict__ bq,
    const float* __restrict__ wk, const float* __restrict__ bk,
    const float* __restrict__ wv, const float* __restrict__ bv,
    unsigned short* __restrict__ wqkf, float* __restrict__ bqk, unsigned short* __restrict__ vtf)
{
    const int bid = blockIdx.x;
    const int t = threadIdx.x;

    if (bid < 256) {
        // role A: v rows -> vtf frags. block = (n, ct of 16 c).
        __shared__ float vred[3][4][16][8];              // 6 KB
        const int n   = bid >> 5;
        const int ct  = bid & 31;
        const int cl  = t & 15;
        const int kko = (t >> 4) & 3;
        const int jq4 = t >> 6;
        const int c   = ct * 16 + cl;

        const float* yb  = y  + ((size_t)n * K_ + kko * 8) * C_ + jq4 * 128;
        const float* wvb = wv + (size_t)c * C_ + jq4 * 128;
        float acc[8] = {0,0,0,0,0,0,0,0};
        #pragma unroll 4
        for (int jj = 0; jj < 32; ++jj) {
            float4 w4 = *(const float4*)(wvb + jj * 4);
            #pragma unroll
            for (int u = 0; u < 8; ++u) {
                float4 y4 = *(const float4*)(yb + (size_t)u * C_ + jj * 4);
                acc[u] += y4.x * w4.x + y4.y * w4.y + y4.z * w4.z + y4.w * w4.w;
            }
        }
        if (jq4 > 0) {
            #pragma unroll
            for (int u = 0; u < 8; ++u) vred[jq4 - 1][kko][cl][u] = acc[u];
        }
        __syncthreads();
        if (jq4 == 0) {
            const float bvc = bv[c];
            unsigned short o[8];
            #pragma unroll
            for (int u = 0; u < 8; ++u) {
                float s = acc[u] + vred[0][kko][cl][u] + vred[1][kko][cl][u]
                        + vred[2][kko][cl][u] + bvc;
                o[u] = f2b(s);
            }
            i32x4 pk = { (int)(o[0] | ((unsigned)o[1] << 16)), (int)(o[2] | ((unsigned)o[3] << 16)),
                         (int)(o[4] | ((unsigned)o[5] << 16)), (int)(o[6] | ((unsigned)o[7] << 16)) };
            *(i32x4*)(vtf + (size_t)n * (K_ * C_) + (size_t)((ct * 64 + kko * 16 + cl) * 8)) = pk;
        }
    } else {
        // role B: krow -> bqk, wqk frags. block = (n, kk)
        __shared__ __align__(16) float kp[2][128];
        __shared__ __align__(16) float kr[128];
        const int b = bid - 256;
        const int n = b >> 5, kk = b & 31;
        const int o = t & 127, half = t >> 7;

        const float* yb  = y  + ((size_t)n * K_ + kk) * C_ + half * 256;
        const float* wkb = wk + (size_t)o * C_ + half * 256;
        float a = 0.f;
        #pragma unroll 4
        for (int jq = 0; jq < 64; ++jq) {
            float4 w4 = *(const float4*)(wkb + jq * 4);
            float4 y4 = *(const float4*)(yb + jq * 4);
            a += y4.x * w4.x + y4.y * w4.y + y4.z * w4.z + y4.w * w4.w;
        }
        kp[half][o] = a;
        __syncthreads();
        if (t < 128) kr[t] = kp[0][t] + kp[1][t] + bk[t];
        __syncthreads();
        if (t < 64) {
            float s = kr[t] * bq[t] + kr[t + 64] * bq[t + 64];
            #pragma unroll
            for (int d = 32; d > 0; d >>= 1) s += __shfl_down(s, d);
            if (t == 0) bqk[n * K_ + kk] = s;
        }
        const int c1 = t, c2 = t + 256;
        float s1 = 0.f, s2 = 0.f;
        for (int oq = 0; oq < 32; ++oq) {
            float4 k4 = *(const float4*)(&kr[oq * 4]);
            const float* wq0 = wq + (size_t)(oq * 4) * C_;
            s1 += k4.x * wq0[c1] + k4.y * wq0[C_ + c1] + k4.z * wq0[2*C_ + c1] + k4.w * wq0[3*C_ + c1];
            s2 += k4.x * wq0[c2] + k4.y * wq0[C_ + c2] + k4.z * wq0[2*C_ + c2] + k4.w * wq0[3*C_ + c2];
        }
        unsigned short* wqf_n = wqkf + (size_t)n * (K_ * C_);
        wqf_n[wqk_idx(kk, c1)] = f2b(s1);
        wqf_n[wqk_idx(kk, c2)] = f2b(s2);
    }
}

__global__ __launch_bounds__(256) void energy_kernel(
    const float* __restrict__ x, const unsigned short* __restrict__ wqkf,
    const float* __restrict__ bqk, unsigned short* __restrict__ attf)
{
    __shared__ __align__(16) unsigned short xl[17408];   // 34 KB padded bf16 x-tile
    __shared__ float e_lds[32][33];                       // 4.2 KB

    const int bid = (blockIdx.x & 7) * 128 + (blockIdx.x >> 3);
    const int n  = bid >> 7;
    const int p0 = (bid & 127) * 32;
    const int t  = threadIdx.x;
    const int w  = t >> 6, l = t & 63;
    const int l15 = l & 15, lg = l >> 4;
    const float* xg = x + (size_t)n * C_ * HW_;

    // ---- Phase 0: stage x-tile -> LDS bf16 (padded subtile), 2-batch pipeline ----
    {
        const float* xp0 = xg + p0;
        const int px4 = (t & 7) * 4;
        const int crow = t >> 3;
        const int pxh = ((px4 >> 4) & 1) * 64 + (px4 & 15);
        const int crowpart = ((crow >> 3) & 3) * 272 + ((crow >> 2) & 1) * 128
                           + (crow & 3) * 16 + pxh;

        float4 ra[4], rb[4];
        #pragma unroll
        for (int u = 0; u < 4; ++u)
            ra[u] = *(const float4*)(xp0 + (size_t)(u * 32 + crow) * HW_ + px4);
        for (int b = 0; b < 4; ++b) {
            if (b < 3) {
                #pragma unroll
                for (int u = 0; u < 4; ++u)
                    rb[u] = *(const float4*)(xp0 + (size_t)((b + 1) * 128 + u * 32 + crow) * HW_ + px4);
            }
            #pragma unroll
            for (int u = 0; u < 4; ++u) {
                const float4 r = ra[u];
                const int elem = (b * 4 + u) * 1088 + crowpart;
                i32x2 pk = { (int)(f2b(r.x) | ((unsigned)f2b(r.y) << 16)),
                             (int)(f2b(r.z) | ((unsigned)f2b(r.w) << 16)) };
                *(i32x2*)(xl + elem) = pk;
            }
            #pragma unroll
            for (int u = 0; u < 4; ++u) ra[u] = rb[u];
        }
    }
    __syncthreads();

    // ---- Phase 1: energy MFMA; A from padded LDS, B-frag depth-2 prefetch ----
    {
        const int pt = w & 1, kt = w >> 1;
        const unsigned short* wqf = wqkf + (size_t)n * (K_ * C_);
        bf16x8 b0 = *(const bf16x8*)(wqf + ((size_t)(0 * 2 + kt) * 64 + l) * 8);
        bf16x8 b1 = *(const bf16x8*)(wqf + ((size_t)(1 * 2 + kt) * 64 + l) * 8);

        f32x4 acc = {0.f, 0.f, 0.f, 0.f};
        for (int cs = 0; cs < 16; ++cs) {
            bf16x8 b2;
            if (cs < 14) b2 = *(const bf16x8*)(wqf + ((size_t)((cs + 2) * 2 + kt) * 64 + l) * 8);
            const unsigned short* xp = xl + cs * 1088 + lg * 272 + pt * 64 + l15;
            const unsigned e0 = xp[0],   e1 = xp[16],  e2 = xp[32],  e3 = xp[48];
            const unsigned e4 = xp[128], e5 = xp[144], e6 = xp[160], e7 = xp[176];
            union { unsigned u[4]; bf16x8 v; } af;
            af.u[0] = e0 | (e1 << 16);  af.u[1] = e2 | (e3 << 16);
            af.u[2] = e4 | (e5 << 16);  af.u[3] = e6 | (e7 << 16);
            acc = __builtin_amdgcn_mfma_f32_16x16x32_bf16(af.v, b0, acc, 0, 0, 0);
            b0 = b1; b1 = b2;
        }
        const float bq_ = bqk[n * K_ + kt * 16 + l15];
        #pragma unroll
        for (int r = 0; r < 4; ++r)
            e_lds[pt * 16 + lg * 4 + r][kt * 16 + l15] = acc[r] + bq_;
    }
    __syncthreads();

    // ---- Phase 2: per-lane softmax for both px rows; store attn B-frags ----
    {
        const float* er0 = e_lds[l15];
        const float* er1 = e_lds[16 + l15];
        float e0[32], e1[32];
        #pragma unroll
        for (int k = 0; k < 32; ++k) { e0[k] = er0[k]; e1[k] = er1[k]; }
        float m0 = e0[0], m1 = e1[0];
        #pragma unroll
        for (int k = 1; k < 32; ++k) { m0 = fmaxf(m0, e0[k]); m1 = fmaxf(m1, e1[k]); }
        float s0 = 0.f, s1 = 0.f;
        #pragma unroll
        for (int k = 0; k < 32; ++k) {
            e0[k] = __expf(e0[k] - m0); s0 += e0[k];
            e1[k] = __expf(e1[k] - m1); s1 += e1[k];
        }
        const float i0 = 1.f / s0, i1 = 1.f / s1;
        unsigned short o0[8], o1[8];
        #pragma unroll
        for (int j = 0; j < 8; ++j) {
            o0[j] = f2b(e0[8 * lg + j] * i0);
            o1[j] = f2b(e1[8 * lg + j] * i1);
        }
        // only the first wave per (l) pair writes?? -> every wave computes the same
        // frags for its two rows; but frag content depends only on (l, row pair),
        // identical across waves. Let wave 0 and 1 write tile0/tile1 respectively
        // to avoid 4x duplicate stores.
        unsigned short* an = attf + (size_t)n * (256 * 64 * 8);
        const int tile0 = (bid & 127) * 2;
        if (w == 0) {
            i32x4 pk = { (int)(o0[0] | ((unsigned)o0[1] << 16)), (int)(o0[2] | ((unsigned)o0[3] << 16)),
                         (int)(o0[4] | ((unsigned)o0[5] << 16)), (int)(o0[6] | ((unsigned)o0[7] << 16)) };
            *(i32x4*)(an + ((size_t)tile0 * 64 + l) * 8) = pk;
        } else if (w == 1) {
            i32x4 pk = { (int)(o1[0] | ((unsigned)o1[1] << 16)), (int)(o1[2] | ((unsigned)o1[3] << 16)),
                         (int)(o1[4] | ((unsigned)o1[5] << 16)), (int)(o1[6] | ((unsigned)o1[7] << 16)) };
            *(i32x4*)(an + ((size_t)(tile0 + 1) * 64 + l) * 8) = pk;
        }
    }
}

__global__ __launch_bounds__(256) void pv_kernel(
    const float* __restrict__ x, const unsigned short* __restrict__ vtf,
    const unsigned short* __restrict__ attf, const float* __restrict__ scale,
    float* __restrict__ out)
{
    // no LDS, no barriers: pure streaming PV + residual
    const int bid = (blockIdx.x & 7) * 128 + (blockIdx.x >> 3);
    const int n  = bid >> 7;
    const int p0 = (bid & 127) * 32;
    const int t  = threadIdx.x;
    const int w  = t >> 6, l = t & 63;
    const int l15 = l & 15, lg = l >> 4;
    const float* xg = x + (size_t)n * C_ * HW_;
    float* og = out + (size_t)n * C_ * HW_;
    const unsigned short* vtfn = vtf + (size_t)n * (K_ * C_);
    const unsigned short* an = attf + (size_t)n * (256 * 64 * 8);
    const float fs = scale[0];

    const int tile0 = (bid & 127) * 2;
    const bf16x8 paf0 = *(const bf16x8*)(an + ((size_t)tile0 * 64 + l) * 8);
    const bf16x8 paf1 = *(const bf16x8*)(an + ((size_t)(tile0 + 1) * 64 + l) * 8);

    const int mh = w;                               // c-quarter
    const int pxa = p0 + l15, pxb = p0 + 16 + l15;
    const int mt0 = mh * 8;

    bf16x8 vcur = *(const bf16x8*)(vtfn + ((size_t)mt0 * 64 + l) * 8);
    float xa0[4], xa1[4];
    {
        const int c0 = mt0 * 16 + lg * 4;
        #pragma unroll
        for (int r = 0; r < 4; ++r) {
            xa0[r] = xg[(size_t)(c0 + r) * HW_ + pxa];
            xa1[r] = xg[(size_t)(c0 + r) * HW_ + pxb];
        }
    }

    for (int mi = 0; mi < 8; ++mi) {
        const int mt = mt0 + mi;
        bf16x8 vnext;
        float xn0[4], xn1[4];
        if (mi < 7) {
            vnext = *(const bf16x8*)(vtfn + ((size_t)(mt + 1) * 64 + l) * 8);
            const int cn = (mt + 1) * 16 + lg * 4;
            #pragma unroll
            for (int r = 0; r < 4; ++r) {
                xn0[r] = xg[(size_t)(cn + r) * HW_ + pxa];
                xn1[r] = xg[(size_t)(cn + r) * HW_ + pxb];
            }
        }
        f32x4 d0 = __builtin_amdgcn_mfma_f32_16x16x32_bf16(vcur, paf0, (f32x4){0.f,0.f,0.f,0.f}, 0, 0, 0);
        f32x4 d1 = __builtin_amdgcn_mfma_f32_16x16x32_bf16(vcur, paf1, (f32x4){0.f,0.f,0.f,0.f}, 0, 0, 0);
        const int cc = mt * 16 + lg * 4;
        #pragma unroll
        for (int r = 0; r < 4; ++r) {
            og[(size_t)(cc + r) * HW_ + pxa] = fs * d0[r] + xa0[r];
            og[(size_t)(cc + r) * HW_ + pxb] = fs * d1[r] + xa1[r];
        }
        vcur = vnext;
        #pragma unroll
        for (int r = 0; r < 4; ++r) { xa0[r] = xn0[r]; xa1[r] = xn1[r]; }
    }
}

extern "C" void kernel_launch(void* const* d_in, const int* in_sizes, int n_in,
                              void* d_out, int out_size, void* d_ws, size_t ws_size,
                              hipStream_t stream) {
    const float* x     = (const float*)d_in[0];
    const float* y     = (const float*)d_in[1];
    const float* wq    = (const float*)d_in[2];
    const float* bq    = (const float*)d_in[3];
    const float* wk    = (const float*)d_in[4];
    const float* bk    = (const float*)d_in[5];
    const float* wv    = (const float*)d_in[6];
    const float* bv    = (const float*)d_in[7];
    const float* scale = (const float*)d_in[8];

    unsigned short* wqkf = (unsigned short*)d_ws;                       // 256 KB
    unsigned short* vtf  = wqkf + (size_t)N_ * K_ * C_;                 // 256 KB
    float* bqk = (float*)((char*)d_ws + 524288);                        // 1 KB
    unsigned short* attf = (unsigned short*)((char*)d_ws + 525312);     // 2 MB

    prep_kernel<<<512, 256, 0, stream>>>(y, wq, bq, wk, bk, wv, bv, wqkf, bqk, vtf);
    energy_kernel<<<1024, 256, 0, stream>>>(x, wqkf, bqk, attf);
    pv_kernel<<<1024, 256, 0, stream>>>(x, vtf, attf, scale, (float*)d_out);
}

// Round 17
// 58.818 us; speedup vs baseline: 1.8242x; 1.2609x over previous
//
#include <hip/hip_runtime.h>

// CPAMDec — R17: R14 (best) + vtf A-frags hoisted to registers pre-phase-0
// (phase 3 loses its L2 dependency chain; loads overlap the x staging read)
// + phase-1 B-frag cold-start prefetch hoisted. Numerics identical to R14.
//   energy[px][kk] = sum_c x_bf[px][c] * wqk_bf[c][kk] (+bqk)
//   out[c][px]     = fs * sum_kk vT_bf[c][kk] * attn_bf[kk][px] + x_bf[c][px]
// Frag layouts (mfma_f32_16x16x32_bf16), HW-verified R5/R6:
//   A[m][k]: lane l -> m=l&15, k=8*(l>>4)+j ; B[k][n]: lane l -> n=l&15, k=8*(l>>4)+j
//   D[m][n]: lane l -> n=l&15, m=4*(l>>4)+r
// xl padded subtile: elem(c,px) = (c>>5)*1088 + ((c>>3)&3)*272 + ((c>>2)&1)*128
//                              + (c&3)*16 + ((px>>4)&1)*64 + (px&15)
// ws: wqkf bf16[N][32*512] @0 | vtf bf16[N][32*512] @256K | bqk f32[256] @512K

#define N_  8
#define C_  512
#define HW_ 4096
#define K_  32

typedef __attribute__((ext_vector_type(8))) short bf16x8;
typedef __attribute__((ext_vector_type(4))) float f32x4;
typedef __attribute__((ext_vector_type(2))) int i32x2;
typedef __attribute__((ext_vector_type(4))) int i32x4;

__device__ __forceinline__ unsigned short f2b(float f) {
    union { float f; unsigned u; } v; v.f = f;
    unsigned r = v.u + 0x7FFFu + ((v.u >> 16) & 1u);   // RNE
    return (unsigned short)(r >> 16);
}
__device__ __forceinline__ float b2f(unsigned short h) {
    union { unsigned u; float f; } v; v.u = ((unsigned)h) << 16; return v.f;
}

// wqk frag slot: wqk[kk][c] -> elem ((cs*2+kt)*64 + g*16 + (kk&15))*8 + j
__device__ __forceinline__ int wqk_idx(int kk, int c) {
    return ((((c >> 5) * 2 + (kk >> 4)) * 64 + ((c >> 3) & 3) * 16 + (kk & 15)) << 3) + (c & 7);
}

__global__ __launch_bounds__(256) void prep_kernel(
    const float* __restrict__ y, const float* __restrict__ wq, const float* __restrict__ bq,
    const float* __restrict__ wk, const float* __restrict__ bk,
    const float* __restrict__ wv, const float* __restrict__ bv,
    unsigned short* __restrict__ wqkf, float* __restrict__ bqk, unsigned short* __restrict__ vtf)
{
    const int bid = blockIdx.x;
    const int t = threadIdx.x;

    if (bid < 256) {
        // role A: v rows -> vtf frags. block = (n, ct of 16 c).
        __shared__ float vred[3][4][16][8];              // 6 KB
        const int n   = bid >> 5;
        const int ct  = bid & 31;
        const int cl  = t & 15;
        const int kko = (t >> 4) & 3;
        const int jq4 = t >> 6;
        const int c   = ct * 16 + cl;

        const float* yb  = y  + ((size_t)n * K_ + kko * 8) * C_ + jq4 * 128;
        const float* wvb = wv + (size_t)c * C_ + jq4 * 128;
        float acc[8] = {0,0,0,0,0,0,0,0};
        #pragma unroll 4
        for (int jj = 0; jj < 32; ++jj) {
            float4 w4 = *(const float4*)(wvb + jj * 4);
            #pragma unroll
            for (int u = 0; u < 8; ++u) {
                float4 y4 = *(const float4*)(yb + (size_t)u * C_ + jj * 4);
                acc[u] += y4.x * w4.x + y4.y * w4.y + y4.z * w4.z + y4.w * w4.w;
            }
        }
        if (jq4 > 0) {
            #pragma unroll
            for (int u = 0; u < 8; ++u) vred[jq4 - 1][kko][cl][u] = acc[u];
        }
        __syncthreads();
        if (jq4 == 0) {
            const float bvc = bv[c];
            unsigned short o[8];
            #pragma unroll
            for (int u = 0; u < 8; ++u) {
                float s = acc[u] + vred[0][kko][cl][u] + vred[1][kko][cl][u]
                        + vred[2][kko][cl][u] + bvc;
                o[u] = f2b(s);
            }
            i32x4 pk = { (int)(o[0] | ((unsigned)o[1] << 16)), (int)(o[2] | ((unsigned)o[3] << 16)),
                         (int)(o[4] | ((unsigned)o[5] << 16)), (int)(o[6] | ((unsigned)o[7] << 16)) };
            *(i32x4*)(vtf + (size_t)n * (K_ * C_) + (size_t)((ct * 64 + kko * 16 + cl) * 8)) = pk;
        }
    } else {
        // role B: krow -> bqk, wqk frags. block = (n, kk)
        __shared__ __align__(16) float kp[2][128];
        __shared__ __align__(16) float kr[128];
        const int b = bid - 256;
        const int n = b >> 5, kk = b & 31;
        const int o = t & 127, half = t >> 7;

        const float* yb  = y  + ((size_t)n * K_ + kk) * C_ + half * 256;
        const float* wkb = wk + (size_t)o * C_ + half * 256;
        float a = 0.f;
        #pragma unroll 4
        for (int jq = 0; jq < 64; ++jq) {
            float4 w4 = *(const float4*)(wkb + jq * 4);
            float4 y4 = *(const float4*)(yb + jq * 4);
            a += y4.x * w4.x + y4.y * w4.y + y4.z * w4.z + y4.w * w4.w;
        }
        kp[half][o] = a;
        __syncthreads();
        if (t < 128) kr[t] = kp[0][t] + kp[1][t] + bk[t];
        __syncthreads();
        if (t < 64) {
            float s = kr[t] * bq[t] + kr[t + 64] * bq[t + 64];
            #pragma unroll
            for (int d = 32; d > 0; d >>= 1) s += __shfl_down(s, d);
            if (t == 0) bqk[n * K_ + kk] = s;
        }
        const int c1 = t, c2 = t + 256;
        float s1 = 0.f, s2 = 0.f;
        for (int oq = 0; oq < 32; ++oq) {
            float4 k4 = *(const float4*)(&kr[oq * 4]);
            const float* wq0 = wq + (size_t)(oq * 4) * C_;
            s1 += k4.x * wq0[c1] + k4.y * wq0[C_ + c1] + k4.z * wq0[2*C_ + c1] + k4.w * wq0[3*C_ + c1];
            s2 += k4.x * wq0[c2] + k4.y * wq0[C_ + c2] + k4.z * wq0[2*C_ + c2] + k4.w * wq0[3*C_ + c2];
        }
        unsigned short* wqf_n = wqkf + (size_t)n * (K_ * C_);
        wqf_n[wqk_idx(kk, c1)] = f2b(s1);
        wqf_n[wqk_idx(kk, c2)] = f2b(s2);
    }
}

__global__ __launch_bounds__(256) void main_kernel(
    const float* __restrict__ x, const unsigned short* __restrict__ wqkf,
    const unsigned short* __restrict__ vtf, const float* __restrict__ bqk,
    const float* __restrict__ scale, float* __restrict__ out)
{
    __shared__ __align__(16) unsigned short xl[17408];   // 34 KB padded bf16 x-tile
    __shared__ float e_lds[32][33];                       // 4.2 KB

    // XCD swizzle: 128 consecutive tiles (= one image n) per XCD
    const int bid = (blockIdx.x & 7) * 128 + (blockIdx.x >> 3);
    const int n  = bid >> 7;
    const int p0 = (bid & 127) * 32;
    const int t  = threadIdx.x;
    const int w  = t >> 6, l = t & 63;
    const int l15 = l & 15, lg = l >> 4;
    const float* xg = x + (size_t)n * C_ * HW_;
    float* og = out + (size_t)n * C_ * HW_;
    const unsigned short* wqf  = wqkf + (size_t)n * (K_ * C_);
    const unsigned short* vtfn = vtf  + (size_t)n * (K_ * C_);

    // ---- Hoisted invariant loads: vtf A-frags (phase 3) + first B-frags (phase 1).
    // Issued before phase 0 so they fly concurrently with the x staging read.
    const int mh = w;                                    // phase-3 c-quarter
    const int kt = w >> 1;                               // phase-1 kk-tile
    bf16x8 vf[8];
    #pragma unroll
    for (int mi = 0; mi < 8; ++mi)
        vf[mi] = *(const bf16x8*)(vtfn + ((size_t)(mh * 8 + mi) * 64 + l) * 8);
    bf16x8 b0 = *(const bf16x8*)(wqf + ((size_t)(0 * 2 + kt) * 64 + l) * 8);
    bf16x8 b1 = *(const bf16x8*)(wqf + ((size_t)(1 * 2 + kt) * 64 + l) * 8);

    // ---- Phase 0: stage x-tile -> LDS bf16 (padded subtile), 2-batch pipeline ----
    {
        const float* xp0 = xg + p0;
        const int px4 = (t & 7) * 4;
        const int crow = t >> 3;
        const int pxh = ((px4 >> 4) & 1) * 64 + (px4 & 15);
        const int crowpart = ((crow >> 3) & 3) * 272 + ((crow >> 2) & 1) * 128
                           + (crow & 3) * 16 + pxh;

        float4 ra[4], rb[4];
        #pragma unroll
        for (int u = 0; u < 4; ++u)
            ra[u] = *(const float4*)(xp0 + (size_t)(u * 32 + crow) * HW_ + px4);
        for (int b = 0; b < 4; ++b) {
            if (b < 3) {
                #pragma unroll
                for (int u = 0; u < 4; ++u)
                    rb[u] = *(const float4*)(xp0 + (size_t)((b + 1) * 128 + u * 32 + crow) * HW_ + px4);
            }
            #pragma unroll
            for (int u = 0; u < 4; ++u) {
                const float4 r = ra[u];
                const int elem = (b * 4 + u) * 1088 + crowpart;
                i32x2 pk = { (int)(f2b(r.x) | ((unsigned)f2b(r.y) << 16)),
                             (int)(f2b(r.z) | ((unsigned)f2b(r.w) << 16)) };
                *(i32x2*)(xl + elem) = pk;
            }
            #pragma unroll
            for (int u = 0; u < 4; ++u) ra[u] = rb[u];
        }
    }
    __syncthreads();

    // ---- Phase 1: energy MFMA; A from padded LDS, B-frag depth-2 prefetch ----
    {
        const int pt = w & 1;
        f32x4 acc = {0.f, 0.f, 0.f, 0.f};
        for (int cs = 0; cs < 16; ++cs) {
            bf16x8 b2;
            if (cs < 14) b2 = *(const bf16x8*)(wqf + ((size_t)((cs + 2) * 2 + kt) * 64 + l) * 8);
            const unsigned short* xp = xl + cs * 1088 + lg * 272 + pt * 64 + l15;
            const unsigned e0 = xp[0],   e1 = xp[16],  e2 = xp[32],  e3 = xp[48];
            const unsigned e4 = xp[128], e5 = xp[144], e6 = xp[160], e7 = xp[176];
            union { unsigned u[4]; bf16x8 v; } af;
            af.u[0] = e0 | (e1 << 16);  af.u[1] = e2 | (e3 << 16);
            af.u[2] = e4 | (e5 << 16);  af.u[3] = e6 | (e7 << 16);
            acc = __builtin_amdgcn_mfma_f32_16x16x32_bf16(af.v, b0, acc, 0, 0, 0);
            b0 = b1; b1 = b2;
        }
        const float bq_ = bqk[n * K_ + kt * 16 + l15];
        #pragma unroll
        for (int r = 0; r < 4; ++r)
            e_lds[pt * 16 + lg * 4 + r][kt * 16 + l15] = acc[r] + bq_;
    }
    __syncthreads();

    // ---- Phase 2: per-lane softmax for BOTH px rows (l15 and 16+l15) ----
    bf16x8 paf0, paf1;
    {
        const float* er0 = e_lds[l15];
        const float* er1 = e_lds[16 + l15];
        float e0[32], e1[32];
        #pragma unroll
        for (int k = 0; k < 32; ++k) { e0[k] = er0[k]; e1[k] = er1[k]; }
        float m0 = e0[0], m1 = e1[0];
        #pragma unroll
        for (int k = 1; k < 32; ++k) { m0 = fmaxf(m0, e0[k]); m1 = fmaxf(m1, e1[k]); }
        float s0 = 0.f, s1 = 0.f;
        #pragma unroll
        for (int k = 0; k < 32; ++k) {
            e0[k] = __expf(e0[k] - m0); s0 += e0[k];
            e1[k] = __expf(e1[k] - m1); s1 += e1[k];
        }
        const float i0 = 1.f / s0, i1 = 1.f / s1;
        #pragma unroll
        for (int j = 0; j < 8; ++j) {
            paf0[j] = (short)f2b(e0[8 * lg + j] * i0);
            paf1[j] = (short)f2b(e1[8 * lg + j] * i1);
        }
    }

    // ---- Phase 3: PV MFMA from hoisted vf; residual from LDS; full-line writes ----
    {
        const float fs = scale[0];
        const int pxa = p0 + l15, pxb = p0 + 16 + l15;
        const int mt0 = mh * 8;

        #pragma unroll
        for (int mi = 0; mi < 8; ++mi) {
            const int mt = mt0 + mi;
            f32x4 d0 = __builtin_amdgcn_mfma_f32_16x16x32_bf16(vf[mi], paf0, (f32x4){0.f,0.f,0.f,0.f}, 0, 0, 0);
            f32x4 d1 = __builtin_amdgcn_mfma_f32_16x16x32_bf16(vf[mi], paf1, (f32x4){0.f,0.f,0.f,0.f}, 0, 0, 0);
            // residual from xl: c = mt*16 + lg*4 + r
            const int base = (mt >> 1) * 1088 + ((mt & 1) * 2 + (lg >> 1)) * 272
                           + (lg & 1) * 128 + l15;
            const int cc = mt * 16 + lg * 4;
            #pragma unroll
            for (int r = 0; r < 4; ++r) {
                const float xa0 = b2f(xl[base + r * 16]);
                const float xa1 = b2f(xl[base + r * 16 + 64]);
                og[(size_t)(cc + r) * HW_ + pxa] = fs * d0[r] + xa0;
                og[(size_t)(cc + r) * HW_ + pxb] = fs * d1[r] + xa1;
            }
        }
    }
}

extern "C" void kernel_launch(void* const* d_in, const int* in_sizes, int n_in,
                              void* d_out, int out_size, void* d_ws, size_t ws_size,
                              hipStream_t stream) {
    const float* x     = (const float*)d_in[0];
    const float* y     = (const float*)d_in[1];
    const float* wq    = (const float*)d_in[2];
    const float* bq    = (const float*)d_in[3];
    const float* wk    = (const float*)d_in[4];
    const float* bk    = (const float*)d_in[5];
    const float* wv    = (const float*)d_in[6];
    const float* bv    = (const float*)d_in[7];
    const float* scale = (const float*)d_in[8];

    unsigned short* wqkf = (unsigned short*)d_ws;                       // 256 KB
    unsigned short* vtf  = wqkf + (size_t)N_ * K_ * C_;                 // 256 KB
    float* bqk = (float*)((char*)d_ws + 524288);                        // 1 KB

    prep_kernel<<<512, 256, 0, stream>>>(y, wq, bq, wk, bk, wv, bv, wqkf, bqk, vtf);
    main_kernel<<<1024, 256, 0, stream>>>(x, wqkf, vtf, bqk, scale, (float*)d_out);
}

// Round 18
// 58.599 us; speedup vs baseline: 1.8310x; 1.0037x over previous
//
#include <hip/hip_runtime.h>

// CPAMDec — R18: vectorized-LDS layout. xl stores x so each A-frag octet is
// contiguous: elem(c,px) = (c>>5)*1024 + ((c>>3)&3)*256 + px*8 + (c&7).
// Phase 1 A-frag = 1 ds_read_b128 (was 8 ds_read_u16 + pack); phase 3 residual
// = 2 ds_read_b64 (was 8 ds_read_u16). Hoisted vf/b-frags kept (R17).
//   energy[px][kk] = sum_c x_bf[px][c] * wqk_bf[c][kk] (+bqk)
//   out[c][px]     = fs * sum_kk vT_bf[c][kk] * attn_bf[kk][px] + x_bf[c][px]
// Frag layouts (mfma_f32_16x16x32_bf16), HW-verified R5/R6:
//   A[m][k]: lane l -> m=l&15, k=8*(l>>4)+j ; B[k][n]: lane l -> n=l&15, k=8*(l>>4)+j
//   D[m][n]: lane l -> n=l&15, m=4*(l>>4)+r
// ws: wqkf bf16[N][32*512] @0 | vtf bf16[N][32*512] @256K | bqk f32[256] @512K

#define N_  8
#define C_  512
#define HW_ 4096
#define K_  32

typedef __attribute__((ext_vector_type(8))) short bf16x8;
typedef __attribute__((ext_vector_type(4))) float f32x4;
typedef __attribute__((ext_vector_type(4))) unsigned short u16x4;
typedef __attribute__((ext_vector_type(2))) int i32x2;
typedef __attribute__((ext_vector_type(4))) int i32x4;

__device__ __forceinline__ unsigned short f2b(float f) {
    union { float f; unsigned u; } v; v.f = f;
    unsigned r = v.u + 0x7FFFu + ((v.u >> 16) & 1u);   // RNE
    return (unsigned short)(r >> 16);
}
__device__ __forceinline__ float b2f(unsigned short h) {
    union { unsigned u; float f; } v; v.u = ((unsigned)h) << 16; return v.f;
}

// wqk frag slot: wqk[kk][c] -> elem ((cs*2+kt)*64 + g*16 + (kk&15))*8 + j
__device__ __forceinline__ int wqk_idx(int kk, int c) {
    return ((((c >> 5) * 2 + (kk >> 4)) * 64 + ((c >> 3) & 3) * 16 + (kk & 15)) << 3) + (c & 7);
}

__global__ __launch_bounds__(256) void prep_kernel(
    const float* __restrict__ y, const float* __restrict__ wq, const float* __restrict__ bq,
    const float* __restrict__ wk, const float* __restrict__ bk,
    const float* __restrict__ wv, const float* __restrict__ bv,
    unsigned short* __restrict__ wqkf, float* __restrict__ bqk, unsigned short* __restrict__ vtf)
{
    const int bid = blockIdx.x;
    const int t = threadIdx.x;

    if (bid < 256) {
        // role A: v rows -> vtf frags. block = (n, ct of 16 c).
        __shared__ float vred[3][4][16][8];              // 6 KB
        const int n   = bid >> 5;
        const int ct  = bid & 31;
        const int cl  = t & 15;
        const int kko = (t >> 4) & 3;
        const int jq4 = t >> 6;
        const int c   = ct * 16 + cl;

        const float* yb  = y  + ((size_t)n * K_ + kko * 8) * C_ + jq4 * 128;
        const float* wvb = wv + (size_t)c * C_ + jq4 * 128;
        float acc[8] = {0,0,0,0,0,0,0,0};
        #pragma unroll 4
        for (int jj = 0; jj < 32; ++jj) {
            float4 w4 = *(const float4*)(wvb + jj * 4);
            #pragma unroll
            for (int u = 0; u < 8; ++u) {
                float4 y4 = *(const float4*)(yb + (size_t)u * C_ + jj * 4);
                acc[u] += y4.x * w4.x + y4.y * w4.y + y4.z * w4.z + y4.w * w4.w;
            }
        }
        if (jq4 > 0) {
            #pragma unroll
            for (int u = 0; u < 8; ++u) vred[jq4 - 1][kko][cl][u] = acc[u];
        }
        __syncthreads();
        if (jq4 == 0) {
            const float bvc = bv[c];
            unsigned short o[8];
            #pragma unroll
            for (int u = 0; u < 8; ++u) {
                float s = acc[u] + vred[0][kko][cl][u] + vred[1][kko][cl][u]
                        + vred[2][kko][cl][u] + bvc;
                o[u] = f2b(s);
            }
            i32x4 pk = { (int)(o[0] | ((unsigned)o[1] << 16)), (int)(o[2] | ((unsigned)o[3] << 16)),
                         (int)(o[4] | ((unsigned)o[5] << 16)), (int)(o[6] | ((unsigned)o[7] << 16)) };
            *(i32x4*)(vtf + (size_t)n * (K_ * C_) + (size_t)((ct * 64 + kko * 16 + cl) * 8)) = pk;
        }
    } else {
        // role B: krow -> bqk, wqk frags. block = (n, kk)
        __shared__ __align__(16) float kp[2][128];
        __shared__ __align__(16) float kr[128];
        const int b = bid - 256;
        const int n = b >> 5, kk = b & 31;
        const int o = t & 127, half = t >> 7;

        const float* yb  = y  + ((size_t)n * K_ + kk) * C_ + half * 256;
        const float* wkb = wk + (size_t)o * C_ + half * 256;
        float a = 0.f;
        #pragma unroll 4
        for (int jq = 0; jq < 64; ++jq) {
            float4 w4 = *(const float4*)(wkb + jq * 4);
            float4 y4 = *(const float4*)(yb + jq * 4);
            a += y4.x * w4.x + y4.y * w4.y + y4.z * w4.z + y4.w * w4.w;
        }
        kp[half][o] = a;
        __syncthreads();
        if (t < 128) kr[t] = kp[0][t] + kp[1][t] + bk[t];
        __syncthreads();
        if (t < 64) {
            float s = kr[t] * bq[t] + kr[t + 64] * bq[t + 64];
            #pragma unroll
            for (int d = 32; d > 0; d >>= 1) s += __shfl_down(s, d);
            if (t == 0) bqk[n * K_ + kk] = s;
        }
        const int c1 = t, c2 = t + 256;
        float s1 = 0.f, s2 = 0.f;
        for (int oq = 0; oq < 32; ++oq) {
            float4 k4 = *(const float4*)(&kr[oq * 4]);
            const float* wq0 = wq + (size_t)(oq * 4) * C_;
            s1 += k4.x * wq0[c1] + k4.y * wq0[C_ + c1] + k4.z * wq0[2*C_ + c1] + k4.w * wq0[3*C_ + c1];
            s2 += k4.x * wq0[c2] + k4.y * wq0[C_ + c2] + k4.z * wq0[2*C_ + c2] + k4.w * wq0[3*C_ + c2];
        }
        unsigned short* wqf_n = wqkf + (size_t)n * (K_ * C_);
        wqf_n[wqk_idx(kk, c1)] = f2b(s1);
        wqf_n[wqk_idx(kk, c2)] = f2b(s2);
    }
}

__global__ __launch_bounds__(256) void main_kernel(
    const float* __restrict__ x, const unsigned short* __restrict__ wqkf,
    const unsigned short* __restrict__ vtf, const float* __restrict__ bqk,
    const float* __restrict__ scale, float* __restrict__ out)
{
    __shared__ __align__(16) unsigned short xl[16384];   // 32 KB, octet-contiguous layout
    __shared__ float e_lds[32][33];                       // 4.2 KB

    // XCD swizzle: 128 consecutive tiles (= one image n) per XCD
    const int bid = (blockIdx.x & 7) * 128 + (blockIdx.x >> 3);
    const int n  = bid >> 7;
    const int p0 = (bid & 127) * 32;
    const int t  = threadIdx.x;
    const int w  = t >> 6, l = t & 63;
    const int l15 = l & 15, lg = l >> 4;
    const float* xg = x + (size_t)n * C_ * HW_;
    float* og = out + (size_t)n * C_ * HW_;
    const unsigned short* wqf  = wqkf + (size_t)n * (K_ * C_);
    const unsigned short* vtfn = vtf  + (size_t)n * (K_ * C_);

    // ---- Hoisted invariant loads (fly concurrently with phase-0 x read) ----
    const int mh = w;                                    // phase-3 c-quarter
    const int kt = w >> 1;                               // phase-1 kk-tile
    bf16x8 vf[8];
    #pragma unroll
    for (int mi = 0; mi < 8; ++mi)
        vf[mi] = *(const bf16x8*)(vtfn + ((size_t)(mh * 8 + mi) * 64 + l) * 8);
    bf16x8 b0 = *(const bf16x8*)(wqf + ((size_t)(0 * 2 + kt) * 64 + l) * 8);
    bf16x8 b1 = *(const bf16x8*)(wqf + ((size_t)(1 * 2 + kt) * 64 + l) * 8);

    // ---- Phase 0: stage x -> LDS (octet layout). lane->px, 8-c octets, 2-batch ----
    {
        const int px = t & 31, g = t >> 5;
        const float* xc = xg + p0 + px;
        float ra[8], rb[8];
        #pragma unroll
        for (int j = 0; j < 8; ++j) ra[j] = xc[(size_t)(g * 8 + j) * HW_];
        for (int u = 0; u < 8; ++u) {
            if (u < 7) {
                #pragma unroll
                for (int j = 0; j < 8; ++j)
                    rb[j] = xc[(size_t)(g * 8 + (u + 1) * 64 + j) * HW_];
            }
            unsigned short o[8];
            #pragma unroll
            for (int j = 0; j < 8; ++j) o[j] = f2b(ra[j]);
            const int cbase = g * 8 + u * 64;
            const int elem = ((cbase >> 5) * 1024) + (((cbase >> 3) & 3) * 256) + px * 8;
            i32x4 pk = { (int)(o[0] | ((unsigned)o[1] << 16)), (int)(o[2] | ((unsigned)o[3] << 16)),
                         (int)(o[4] | ((unsigned)o[5] << 16)), (int)(o[6] | ((unsigned)o[7] << 16)) };
            *(i32x4*)(xl + elem) = pk;
            #pragma unroll
            for (int j = 0; j < 8; ++j) ra[j] = rb[j];
        }
    }
    __syncthreads();

    // ---- Phase 1: energy MFMA; A = single ds_read_b128 per cs ----
    {
        const int pt = w & 1;
        const unsigned short* xbase = xl + lg * 256 + (pt * 16 + l15) * 8;
        f32x4 acc = {0.f, 0.f, 0.f, 0.f};
        for (int cs = 0; cs < 16; ++cs) {
            bf16x8 b2;
            if (cs < 14) b2 = *(const bf16x8*)(wqf + ((size_t)((cs + 2) * 2 + kt) * 64 + l) * 8);
            const bf16x8 af = *(const bf16x8*)(xbase + cs * 1024);
            acc = __builtin_amdgcn_mfma_f32_16x16x32_bf16(af, b0, acc, 0, 0, 0);
            b0 = b1; b1 = b2;
        }
        const float bq_ = bqk[n * K_ + kt * 16 + l15];
        #pragma unroll
        for (int r = 0; r < 4; ++r)
            e_lds[pt * 16 + lg * 4 + r][kt * 16 + l15] = acc[r] + bq_;
    }
    __syncthreads();

    // ---- Phase 2: per-lane softmax for BOTH px rows (l15 and 16+l15) ----
    bf16x8 paf0, paf1;
    {
        const float* er0 = e_lds[l15];
        const float* er1 = e_lds[16 + l15];
        float e0[32], e1[32];
        #pragma unroll
        for (int k = 0; k < 32; ++k) { e0[k] = er0[k]; e1[k] = er1[k]; }
        float m0 = e0[0], m1 = e1[0];
        #pragma unroll
        for (int k = 1; k < 32; ++k) { m0 = fmaxf(m0, e0[k]); m1 = fmaxf(m1, e1[k]); }
        float s0 = 0.f, s1 = 0.f;
        #pragma unroll
        for (int k = 0; k < 32; ++k) {
            e0[k] = __expf(e0[k] - m0); s0 += e0[k];
            e1[k] = __expf(e1[k] - m1); s1 += e1[k];
        }
        const float i0 = 1.f / s0, i1 = 1.f / s1;
        #pragma unroll
        for (int j = 0; j < 8; ++j) {
            paf0[j] = (short)f2b(e0[8 * lg + j] * i0);
            paf1[j] = (short)f2b(e1[8 * lg + j] * i1);
        }
    }

    // ---- Phase 3: PV MFMA from hoisted vf; residual = 2 ds_read_b64/mi ----
    {
        const float fs = scale[0];
        const int pxa = p0 + l15, pxb = p0 + 16 + l15;
        const int mt0 = mh * 8;

        #pragma unroll
        for (int mi = 0; mi < 8; ++mi) {
            const int mt = mt0 + mi;
            f32x4 d0 = __builtin_amdgcn_mfma_f32_16x16x32_bf16(vf[mi], paf0, (f32x4){0.f,0.f,0.f,0.f}, 0, 0, 0);
            f32x4 d1 = __builtin_amdgcn_mfma_f32_16x16x32_bf16(vf[mi], paf1, (f32x4){0.f,0.f,0.f,0.f}, 0, 0, 0);
            // residual: c = mt*16 + lg*4 + r -> elem = (mt>>1)*1024
            //   + ((2*mt+(lg>>1))&3)*256 + px*8 + (lg&1)*4 + r
            const int base = (mt >> 1) * 1024 + ((2 * mt + (lg >> 1)) & 3) * 256 + (lg & 1) * 4;
            const u16x4 ra = *(const u16x4*)(xl + base + l15 * 8);
            const u16x4 rb = *(const u16x4*)(xl + base + (16 + l15) * 8);
            const int cc = mt * 16 + lg * 4;
            #pragma unroll
            for (int r = 0; r < 4; ++r) {
                og[(size_t)(cc + r) * HW_ + pxa] = fs * d0[r] + b2f(ra[r]);
                og[(size_t)(cc + r) * HW_ + pxb] = fs * d1[r] + b2f(rb[r]);
            }
        }
    }
}

extern "C" void kernel_launch(void* const* d_in, const int* in_sizes, int n_in,
                              void* d_out, int out_size, void* d_ws, size_t ws_size,
                              hipStream_t stream) {
    const float* x     = (const float*)d_in[0];
    const float* y     = (const float*)d_in[1];
    const float* wq    = (const float*)d_in[2];
    const float* bq    = (const float*)d_in[3];
    const float* wk    = (const float*)d_in[4];
    const float* bk    = (const float*)d_in[5];
    const float* wv    = (const float*)d_in[6];
    const float* bv    = (const float*)d_in[7];
    const float* scale = (const float*)d_in[8];

    unsigned short* wqkf = (unsigned short*)d_ws;                       // 256 KB
    unsigned short* vtf  = wqkf + (size_t)N_ * K_ * C_;                 // 256 KB
    float* bqk = (float*)((char*)d_ws + 524288);                        // 1 KB

    prep_kernel<<<512, 256, 0, stream>>>(y, wq, bq, wk, bk, wv, bv, wqkf, bqk, vtf);
    main_kernel<<<1024, 256, 0, stream>>>(x, wqkf, vtf, bqk, scale, (float*)d_out);
}

// Round 19
// 54.734 us; speedup vs baseline: 1.9603x; 1.0706x over previous
//
#include <hip/hip_runtime.h>

// CPAMDec — R19: R18 + split-barrier software pipeline (half-tile staging with
// 32 loads in flight; half1 loads issued under phase-1a MFMAs) + v_cvt_pk_bf16_f32
// packing + float4 softmax reads (pad 36). All frag formulas HW-verified R5/R6.
//   energy[px][kk] = sum_c x_bf[px][c] * wqk_bf[c][kk] (+bqk)
//   out[c][px]     = fs * sum_kk vT_bf[c][kk] * attn_bf[kk][px] + x_bf[c][px]
// xl octet layout: elem(c,px) = (c>>5)*1024 + ((c>>3)&3)*256 + px*8 + (c&7)
// ws: wqkf bf16[N][32*512] @0 | vtf bf16[N][32*512] @256K | bqk f32[256] @512K

#define N_  8
#define C_  512
#define HW_ 4096
#define K_  32

typedef __attribute__((ext_vector_type(8))) short bf16x8;
typedef __attribute__((ext_vector_type(4))) float f32x4;
typedef __attribute__((ext_vector_type(4))) unsigned short u16x4;
typedef __attribute__((ext_vector_type(4))) int i32x4;

__device__ __forceinline__ unsigned short f2b(float f) {
    union { float f; unsigned u; } v; v.f = f;
    unsigned r = v.u + 0x7FFFu + ((v.u >> 16) & 1u);   // RNE
    return (unsigned short)(r >> 16);
}
__device__ __forceinline__ float b2f(unsigned short h) {
    union { unsigned u; float f; } v; v.u = ((unsigned)h) << 16; return v.f;
}
__device__ __forceinline__ int cvtpk(float a, float b) {   // bf16(a) | bf16(b)<<16, RNE
    int r;
    asm("v_cvt_pk_bf16_f32 %0, %1, %2" : "=v"(r) : "v"(a), "v"(b));
    return r;
}

// wqk frag slot: wqk[kk][c] -> elem ((cs*2+kt)*64 + g*16 + (kk&15))*8 + j
__device__ __forceinline__ int wqk_idx(int kk, int c) {
    return ((((c >> 5) * 2 + (kk >> 4)) * 64 + ((c >> 3) & 3) * 16 + (kk & 15)) << 3) + (c & 7);
}

__global__ __launch_bounds__(256) void prep_kernel(
    const float* __restrict__ y, const float* __restrict__ wq, const float* __restrict__ bq,
    const float* __restrict__ wk, const float* __restrict__ bk,
    const float* __restrict__ wv, const float* __restrict__ bv,
    unsigned short* __restrict__ wqkf, float* __restrict__ bqk, unsigned short* __restrict__ vtf)
{
    const int bid = blockIdx.x;
    const int t = threadIdx.x;

    if (bid < 256) {
        // role A: v rows -> vtf frags. block = (n, ct of 16 c).
        __shared__ float vred[3][4][16][8];              // 6 KB
        const int n   = bid >> 5;
        const int ct  = bid & 31;
        const int cl  = t & 15;
        const int kko = (t >> 4) & 3;
        const int jq4 = t >> 6;
        const int c   = ct * 16 + cl;

        const float* yb  = y  + ((size_t)n * K_ + kko * 8) * C_ + jq4 * 128;
        const float* wvb = wv + (size_t)c * C_ + jq4 * 128;
        float acc[8] = {0,0,0,0,0,0,0,0};
        #pragma unroll 4
        for (int jj = 0; jj < 32; ++jj) {
            float4 w4 = *(const float4*)(wvb + jj * 4);
            #pragma unroll
            for (int u = 0; u < 8; ++u) {
                float4 y4 = *(const float4*)(yb + (size_t)u * C_ + jj * 4);
                acc[u] += y4.x * w4.x + y4.y * w4.y + y4.z * w4.z + y4.w * w4.w;
            }
        }
        if (jq4 > 0) {
            #pragma unroll
            for (int u = 0; u < 8; ++u) vred[jq4 - 1][kko][cl][u] = acc[u];
        }
        __syncthreads();
        if (jq4 == 0) {
            const float bvc = bv[c];
            unsigned short o[8];
            #pragma unroll
            for (int u = 0; u < 8; ++u) {
                float s = acc[u] + vred[0][kko][cl][u] + vred[1][kko][cl][u]
                        + vred[2][kko][cl][u] + bvc;
                o[u] = f2b(s);
            }
            i32x4 pk = { (int)(o[0] | ((unsigned)o[1] << 16)), (int)(o[2] | ((unsigned)o[3] << 16)),
                         (int)(o[4] | ((unsigned)o[5] << 16)), (int)(o[6] | ((unsigned)o[7] << 16)) };
            *(i32x4*)(vtf + (size_t)n * (K_ * C_) + (size_t)((ct * 64 + kko * 16 + cl) * 8)) = pk;
        }
    } else {
        // role B: krow -> bqk, wqk frags. block = (n, kk)
        __shared__ __align__(16) float kp[2][128];
        __shared__ __align__(16) float kr[128];
        const int b = bid - 256;
        const int n = b >> 5, kk = b & 31;
        const int o = t & 127, half = t >> 7;

        const float* yb  = y  + ((size_t)n * K_ + kk) * C_ + half * 256;
        const float* wkb = wk + (size_t)o * C_ + half * 256;
        float a = 0.f;
        #pragma unroll 4
        for (int jq = 0; jq < 64; ++jq) {
            float4 w4 = *(const float4*)(wkb + jq * 4);
            float4 y4 = *(const float4*)(yb + jq * 4);
            a += y4.x * w4.x + y4.y * w4.y + y4.z * w4.z + y4.w * w4.w;
        }
        kp[half][o] = a;
        __syncthreads();
        if (t < 128) kr[t] = kp[0][t] + kp[1][t] + bk[t];
        __syncthreads();
        if (t < 64) {
            float s = kr[t] * bq[t] + kr[t + 64] * bq[t + 64];
            #pragma unroll
            for (int d = 32; d > 0; d >>= 1) s += __shfl_down(s, d);
            if (t == 0) bqk[n * K_ + kk] = s;
        }
        const int c1 = t, c2 = t + 256;
        float s1 = 0.f, s2 = 0.f;
        for (int oq = 0; oq < 32; ++oq) {
            float4 k4 = *(const float4*)(&kr[oq * 4]);
            const float* wq0 = wq + (size_t)(oq * 4) * C_;
            s1 += k4.x * wq0[c1] + k4.y * wq0[C_ + c1] + k4.z * wq0[2*C_ + c1] + k4.w * wq0[3*C_ + c1];
            s2 += k4.x * wq0[c2] + k4.y * wq0[C_ + c2] + k4.z * wq0[2*C_ + c2] + k4.w * wq0[3*C_ + c2];
        }
        unsigned short* wqf_n = wqkf + (size_t)n * (K_ * C_);
        wqf_n[wqk_idx(kk, c1)] = f2b(s1);
        wqf_n[wqk_idx(kk, c2)] = f2b(s2);
    }
}

__global__ __launch_bounds__(256) void main_kernel(
    const float* __restrict__ x, const unsigned short* __restrict__ wqkf,
    const unsigned short* __restrict__ vtf, const float* __restrict__ bqk,
    const float* __restrict__ scale, float* __restrict__ out)
{
    __shared__ __align__(16) unsigned short xl[16384];   // 32 KB, octet-contiguous
    __shared__ float e_lds[32][36];                       // 4.6 KB, 16B-aligned rows

    // XCD swizzle: 128 consecutive tiles (= one image n) per XCD
    const int bid = (blockIdx.x & 7) * 128 + (blockIdx.x >> 3);
    const int n  = bid >> 7;
    const int p0 = (bid & 127) * 32;
    const int t  = threadIdx.x;
    const int w  = t >> 6, l = t & 63;
    const int l15 = l & 15, lg = l >> 4;
    const float* xg = x + (size_t)n * C_ * HW_;
    float* og = out + (size_t)n * C_ * HW_;
    const unsigned short* wqf  = wqkf + (size_t)n * (K_ * C_);
    const unsigned short* vtfn = vtf  + (size_t)n * (K_ * C_);

    // ---- Hoisted invariant loads (fly concurrently with half-0 staging) ----
    const int mh = w;                                    // phase-3 c-quarter
    const int kt = w >> 1;                               // phase-1 kk-tile
    bf16x8 vf[8];
    #pragma unroll
    for (int mi = 0; mi < 8; ++mi)
        vf[mi] = *(const bf16x8*)(vtfn + ((size_t)(mh * 8 + mi) * 64 + l) * 8);
    bf16x8 b0 = *(const bf16x8*)(wqf + ((size_t)(0 * 2 + kt) * 64 + l) * 8);
    bf16x8 b1 = *(const bf16x8*)(wqf + ((size_t)(1 * 2 + kt) * 64 + l) * 8);

    const int px = t & 31, g = t >> 5;
    const float* xc = xg + p0 + px;
    const int pt = w & 1;
    f32x4 acc = {0.f, 0.f, 0.f, 0.f};
    const unsigned short* xbase = xl + lg * 256 + (pt * 16 + l15) * 8;

    // ---- Stage half 0 (octets 0-3 = cs 0-7): 32 loads in flight, then write ----
    {
        float r0[4][8];
        #pragma unroll
        for (int u = 0; u < 4; ++u)
            #pragma unroll
            for (int j = 0; j < 8; ++j)
                r0[u][j] = xc[(size_t)(g * 8 + u * 64 + j) * HW_];
        #pragma unroll
        for (int u = 0; u < 4; ++u) {
            const int cbase = g * 8 + u * 64;
            const int elem = ((cbase >> 5) * 1024) + (((cbase >> 3) & 3) * 256) + px * 8;
            i32x4 pk = { cvtpk(r0[u][0], r0[u][1]), cvtpk(r0[u][2], r0[u][3]),
                         cvtpk(r0[u][4], r0[u][5]), cvtpk(r0[u][6], r0[u][7]) };
            *(i32x4*)(xl + elem) = pk;
        }
    }
    __syncthreads();

    // ---- Issue half-1 loads; phase-1a MFMAs (cs 0-7) run underneath; write half 1 ----
    {
        float r1[4][8];
        #pragma unroll
        for (int u = 0; u < 4; ++u)
            #pragma unroll
            for (int j = 0; j < 8; ++j)
                r1[u][j] = xc[(size_t)(g * 8 + (u + 4) * 64 + j) * HW_];

        for (int cs = 0; cs < 8; ++cs) {
            bf16x8 b2 = *(const bf16x8*)(wqf + ((size_t)((cs + 2) * 2 + kt) * 64 + l) * 8);
            const bf16x8 af = *(const bf16x8*)(xbase + cs * 1024);
            acc = __builtin_amdgcn_mfma_f32_16x16x32_bf16(af, b0, acc, 0, 0, 0);
            b0 = b1; b1 = b2;
        }

        #pragma unroll
        for (int u = 0; u < 4; ++u) {
            const int cbase = g * 8 + (u + 4) * 64;
            const int elem = ((cbase >> 5) * 1024) + (((cbase >> 3) & 3) * 256) + px * 8;
            i32x4 pk = { cvtpk(r1[u][0], r1[u][1]), cvtpk(r1[u][2], r1[u][3]),
                         cvtpk(r1[u][4], r1[u][5]), cvtpk(r1[u][6], r1[u][7]) };
            *(i32x4*)(xl + elem) = pk;
        }
    }
    __syncthreads();

    // ---- Phase 1b: cs 8-15 ----
    {
        for (int cs = 8; cs < 16; ++cs) {
            bf16x8 b2;
            if (cs < 14) b2 = *(const bf16x8*)(wqf + ((size_t)((cs + 2) * 2 + kt) * 64 + l) * 8);
            const bf16x8 af = *(const bf16x8*)(xbase + cs * 1024);
            acc = __builtin_amdgcn_mfma_f32_16x16x32_bf16(af, b0, acc, 0, 0, 0);
            b0 = b1; b1 = b2;
        }
        const float bq_ = bqk[n * K_ + kt * 16 + l15];
        #pragma unroll
        for (int r = 0; r < 4; ++r)
            e_lds[pt * 16 + lg * 4 + r][kt * 16 + l15] = acc[r] + bq_;
    }
    __syncthreads();

    // ---- Phase 2: per-lane softmax (float4 reads), cvt_pk pack ----
    bf16x8 paf0, paf1;
    {
        float e0[32], e1[32];
        #pragma unroll
        for (int i = 0; i < 8; ++i) {
            float4 q0 = *(const float4*)&e_lds[l15][4 * i];
            float4 q1 = *(const float4*)&e_lds[16 + l15][4 * i];
            e0[4*i] = q0.x; e0[4*i+1] = q0.y; e0[4*i+2] = q0.z; e0[4*i+3] = q0.w;
            e1[4*i] = q1.x; e1[4*i+1] = q1.y; e1[4*i+2] = q1.z; e1[4*i+3] = q1.w;
        }
        float m0 = e0[0], m1 = e1[0];
        #pragma unroll
        for (int k = 1; k < 32; ++k) { m0 = fmaxf(m0, e0[k]); m1 = fmaxf(m1, e1[k]); }
        float s0 = 0.f, s1 = 0.f;
        #pragma unroll
        for (int k = 0; k < 32; ++k) {
            e0[k] = __expf(e0[k] - m0); s0 += e0[k];
            e1[k] = __expf(e1[k] - m1); s1 += e1[k];
        }
        const float i0 = 1.f / s0, i1 = 1.f / s1;
        union { int i[4]; bf16x8 v; } u0, u1;
        #pragma unroll
        for (int jj = 0; jj < 4; ++jj) {
            u0.i[jj] = cvtpk(e0[8*lg + 2*jj] * i0, e0[8*lg + 2*jj + 1] * i0);
            u1.i[jj] = cvtpk(e1[8*lg + 2*jj] * i1, e1[8*lg + 2*jj + 1] * i1);
        }
        paf0 = u0.v; paf1 = u1.v;
    }

    // ---- Phase 3: PV MFMA from hoisted vf; residual = 2 ds_read_b64/mi ----
    {
        const float fs = scale[0];
        const int pxa = p0 + l15, pxb = p0 + 16 + l15;
        const int mt0 = mh * 8;

        #pragma unroll
        for (int mi = 0; mi < 8; ++mi) {
            const int mt = mt0 + mi;
            f32x4 d0 = __builtin_amdgcn_mfma_f32_16x16x32_bf16(vf[mi], paf0, (f32x4){0.f,0.f,0.f,0.f}, 0, 0, 0);
            f32x4 d1 = __builtin_amdgcn_mfma_f32_16x16x32_bf16(vf[mi], paf1, (f32x4){0.f,0.f,0.f,0.f}, 0, 0, 0);
            const int base = (mt >> 1) * 1024 + ((2 * mt + (lg >> 1)) & 3) * 256 + (lg & 1) * 4;
            const u16x4 ra = *(const u16x4*)(xl + base + l15 * 8);
            const u16x4 rb = *(const u16x4*)(xl + base + (16 + l15) * 8);
            const int cc = mt * 16 + lg * 4;
            #pragma unroll
            for (int r = 0; r < 4; ++r) {
                og[(size_t)(cc + r) * HW_ + pxa] = fs * d0[r] + b2f(ra[r]);
                og[(size_t)(cc + r) * HW_ + pxb] = fs * d1[r] + b2f(rb[r]);
            }
        }
    }
}

extern "C" void kernel_launch(void* const* d_in, const int* in_sizes, int n_in,
                              void* d_out, int out_size, void* d_ws, size_t ws_size,
                              hipStream_t stream) {
    const float* x     = (const float*)d_in[0];
    const float* y     = (const float*)d_in[1];
    const float* wq    = (const float*)d_in[2];
    const float* bq    = (const float*)d_in[3];
    const float* wk    = (const float*)d_in[4];
    const float* bk    = (const float*)d_in[5];
    const float* wv    = (const float*)d_in[6];
    const float* bv    = (const float*)d_in[7];
    const float* scale = (const float*)d_in[8];

    unsigned short* wqkf = (unsigned short*)d_ws;                       // 256 KB
    unsigned short* vtf  = wqkf + (size_t)N_ * K_ * C_;                 // 256 KB
    float* bqk = (float*)((char*)d_ws + 524288);                        // 1 KB

    prep_kernel<<<512, 256, 0, stream>>>(y, wq, bq, wk, bk, wv, bv, wqkf, bqk, vtf);
    main_kernel<<<1024, 256, 0, stream>>>(x, wqkf, vtf, bqk, scale, (float*)d_out);
}